// Round 3
// baseline (355.127 us; speedup 1.0000x reference)
//
#include <hip/hip_runtime.h>

// MCR^2 loss, m x p fp32 x, labels y in [0,K). m=262144, p=128, K=10.
#define K 10
#define P 128
#define EPSV 0.01f
#define GAM1 1.0f
#define GAM2 1.0f
#define CH 512      // rows per gram block (class segments padded to multiple of CH)
#define SK 64       // staged rows (k-depth) per LDS stage
#define KS 68       // LDS k-stride in bf16 elems (64 + 4 pad, keeps b64s 2-way-free)
#define SORTCH 2048 // rows per sort block
#define NTHR 256

typedef __attribute__((ext_vector_type(8))) short bf16x8;
typedef __attribute__((ext_vector_type(4))) short s16x4;
typedef __attribute__((ext_vector_type(4))) float f32x4;

static __device__ __forceinline__ short f2bf(float f) {
    unsigned u = __float_as_uint(f);
    u = (u + 0x7FFFu + ((u >> 16) & 1u)) >> 16;   // RNE
    return (short)u;
}

// ---------------- histogram per sort-block ----------------
__global__ void hist_kernel(const int* __restrict__ y, int* __restrict__ blk_counts, int m) {
    __shared__ int h[K];
    int t = threadIdx.x;
    if (t < K) h[t] = 0;
    __syncthreads();
    int base = blockIdx.x * SORTCH;
    int rows = min(SORTCH, m - base);
    for (int i = t; i < rows; i += NTHR) atomicAdd(&h[y[base + i]], 1);
    __syncthreads();
    if (t < K) blk_counts[blockIdx.x * K + t] = h[t];
}

// ---------------- parallel scan of block counts; padded class starts ----------
__global__ void scan_kernel(const int* __restrict__ blk_counts, int* __restrict__ blk_offsets,
                            int* __restrict__ counts, int* __restrict__ pstart, int nb) {
    __shared__ int s[K][128];
    __shared__ int sps[K + 1];
    int t = threadIdx.x;
    int own[K];
    if (t < 128) {
        for (int c = 0; c < K; ++c) {
            int v = (t < nb) ? blk_counts[t * K + c] : 0;
            own[c] = v;
            s[c][t] = v;
        }
    }
    __syncthreads();
    for (int off = 1; off < 128; off <<= 1) {
        int tmp[K];
        if (t < 128)
            for (int c = 0; c < K; ++c) tmp[c] = (t >= off) ? s[c][t - off] : 0;
        __syncthreads();
        if (t < 128)
            for (int c = 0; c < K; ++c) s[c][t] += tmp[c];
        __syncthreads();
    }
    if (t == 0) {
        int run = 0;
        for (int c = 0; c < K; ++c) {
            sps[c] = run;
            int tot = s[c][127];
            counts[c] = tot;
            pstart[c] = run;
            run += ((tot + CH - 1) / CH) * CH;   // pad each class to multiple of CH
        }
        sps[K] = run;
        pstart[K] = run;
    }
    __syncthreads();
    if (t < nb)
        for (int c = 0; c < K; ++c)
            blk_offsets[t * K + c] = sps[c] + s[c][t] - own[c];   // exclusive + padded base
}

// ---------------- scatter row indices into padded class-sorted perm -----------
__global__ void scatter_kernel(const int* __restrict__ y, const int* __restrict__ blk_offsets,
                               int* __restrict__ perm, int m) {
    __shared__ int cur[K];
    int t = threadIdx.x;
    if (t < K) cur[t] = blk_offsets[blockIdx.x * K + t];
    __syncthreads();
    int base = blockIdx.x * SORTCH;
    int rows = min(SORTCH, m - base);
    for (int i = t; i < rows; i += NTHR) {
        int row = base + i;
        int pos = atomicAdd(&cur[y[row]], 1);
        perm[pos] = row;
    }
}

// ---------------- per-class Gram via bf16 MFMA --------------------------------
__global__ __launch_bounds__(NTHR) void gram_kernel(const float* __restrict__ x,
                                                    const int* __restrict__ perm,
                                                    const int* __restrict__ pstart,
                                                    float* __restrict__ grams) {
    __shared__ int pm[CH];
    __shared__ short xsT[P * KS];   // 17408 B
    int t = threadIdx.x;
    long base = (long)blockIdx.x * CH;
    int cls = 0;
    for (int c = 1; c < K; ++c)
        if (base >= (long)pstart[c]) cls = c;
    for (int i = t; i < CH; i += NTHR) pm[i] = perm[base + i];

    const int lane = t & 63;
    const int wave = t >> 6;
    const int m16 = lane & 15;
    const int quad = lane >> 4;
    const int wr = wave >> 1;   // tile-row half (gram rows wr*64..+64)
    const int wc = wave & 1;    // tile-col half
    const int c2 = t & 63;      // staging: float2 column pair (cols 2*c2, 2*c2+1)
    const int rg = t >> 6;      // staging: row group of 16

    f32x4 acc[4][4];
#pragma unroll
    for (int a = 0; a < 4; ++a)
#pragma unroll
        for (int b = 0; b < 4; ++b) acc[a][b] = (f32x4){0.f, 0.f, 0.f, 0.f};

    __syncthreads();   // pm visible

    for (int s = 0; s < CH / SK; ++s) {
        int sb = s * SK;
        float2 v[16];
#pragma unroll
        for (int ii = 0; ii < 16; ++ii) {
            int r = pm[sb + rg * 16 + ii];
            if (r >= 0) v[ii] = ((const float2*)(x + (size_t)r * P))[c2];
            else { v[ii].x = 0.f; v[ii].y = 0.f; }
        }
        __syncthreads();   // prior stage fully consumed
        short b0[16], b1[16];
#pragma unroll
        for (int ii = 0; ii < 16; ++ii) { b0[ii] = f2bf(v[ii].x); b1[ii] = f2bf(v[ii].y); }
        int col0 = 2 * c2, col1 = 2 * c2 + 1;
#pragma unroll
        for (int q = 0; q < 4; ++q) {
            s16x4 w0 = {b0[q * 4], b0[q * 4 + 1], b0[q * 4 + 2], b0[q * 4 + 3]};
            s16x4 w1 = {b1[q * 4], b1[q * 4 + 1], b1[q * 4 + 2], b1[q * 4 + 3]};
            *(s16x4*)&xsT[col0 * KS + rg * 16 + q * 4] = w0;
            *(s16x4*)&xsT[col1 * KS + rg * 16 + q * 4] = w1;
        }
        __syncthreads();
#pragma unroll
        for (int kk = 0; kk < 2; ++kk) {
            int k0 = kk * 32 + quad * 8;
            bf16x8 af[4], bfr[4];
#pragma unroll
            for (int a = 0; a < 4; ++a) {
                int colA = wr * 64 + a * 16 + m16;
                union { bf16x8 v8; s16x4 h[2]; } u;
                u.h[0] = *(s16x4*)&xsT[colA * KS + k0];
                u.h[1] = *(s16x4*)&xsT[colA * KS + k0 + 4];
                af[a] = u.v8;
            }
#pragma unroll
            for (int b = 0; b < 4; ++b) {
                int colB = wc * 64 + b * 16 + m16;
                union { bf16x8 v8; s16x4 h[2]; } u;
                u.h[0] = *(s16x4*)&xsT[colB * KS + k0];
                u.h[1] = *(s16x4*)&xsT[colB * KS + k0 + 4];
                bfr[b] = u.v8;
            }
#pragma unroll
            for (int a = 0; a < 4; ++a)
#pragma unroll
                for (int b = 0; b < 4; ++b)
                    acc[a][b] = __builtin_amdgcn_mfma_f32_16x16x32_bf16(af[a], bfr[b], acc[a][b], 0, 0, 0);
        }
    }
    float* g = grams + (size_t)cls * P * P;
#pragma unroll
    for (int a = 0; a < 4; ++a)
#pragma unroll
        for (int b = 0; b < 4; ++b)
#pragma unroll
            for (int r = 0; r < 4; ++r) {
                int gi = wr * 64 + a * 16 + quad * 4 + r;
                int gj = wc * 64 + b * 16 + m16;
                if (gi <= gj) atomicAdd(&g[gi * P + gj], acc[a][b][r]);
            }
}

// ---------------- logdet(I + s*G): blocked symmetric LU, NB=32, 4 block steps -
// Per block step (j0 = 32*bs):
//  phase1 (wave 0, in registers): LU of 32x32 diag block, row-per-lane, shfl
//          broadcasts; accumulates sum log(u_jj); writes 1/u_jj to A diag.
//  phase2 (wave 0, in registers): U12 = L11^-1 A12, column-per-lane forward
//          substitution; writes U12 rows back (row-contiguous, conflict-free).
//  SYRK  (all 256 threads): A22 -= U12^T * D^-1 * U12 using ONLY upper rows
//          (row-contiguous b128 reads), 4x4 register tiles.
__global__ __launch_bounds__(256) void logdet_kernel(const float* __restrict__ grams,
                                                     const int* __restrict__ counts,
                                                     float* __restrict__ logd, int m) {
    __shared__ float A[P * P];   // 64 KB
    int t = threadIdx.x, b = blockIdx.x;
    float scale;
    if (b == 0) scale = GAM1 * (float)P / ((float)m * EPSV);
    else if (b == 1) scale = (float)P / ((float)m * EPSV);
    else {
        float cnt = (float)counts[b - 2];
        if (cnt < 1.f) cnt = 1.f;
        scale = (float)P / (cnt * EPSV);
    }
    for (int idx = t; idx < P * P; idx += 256) {
        int i = idx >> 7, c = idx & (P - 1);
        int src = (i <= c) ? (i * P + c) : (c * P + i);   // grams hold upper triangle
        float sgm;
        if (b < 2) {
            float ssum = 0.f;
            for (int cc = 0; cc < K; ++cc) ssum += grams[cc * P * P + src];
            sgm = ssum;
        } else {
            sgm = grams[(b - 2) * P * P + src];
        }
        A[idx] = scale * sgm + ((i == c) ? 1.f : 0.f);
    }
    __syncthreads();

    const int lane = t & 63;
    const int wid = t >> 6;
    float lsum = 0.f;

    for (int bs = 0; bs < 4; ++bs) {
        const int j0 = bs * 32;
        if (wid == 0) {
            // ---- phase 1: in-register LU of A[j0:j0+32, j0:j0+32] ----
            float a[32];
            if (lane < 32) {
#pragma unroll
                for (int cc = 0; cc < 8; ++cc)
                    *(f32x4*)&a[cc * 4] = *(f32x4*)&A[(j0 + lane) * P + j0 + cc * 4];
            } else {
#pragma unroll
                for (int cc = 0; cc < 32; ++cc) a[cc] = 0.f;
            }
            float myinv = 0.f;
#pragma unroll
            for (int tt = 0; tt < 32; ++tt) {
                float utt = __shfl(a[tt], tt);
                float inv = __builtin_amdgcn_rcpf(utt);
                lsum += __logf(utt);
                if (lane == tt) myinv = inv;
                bool act = (lane < 32) && (lane > tt);
                float lm = act ? a[tt] * inv : 0.f;
                if (act) a[tt] = lm;     // store scaled L entry (needed by phase 2)
#pragma unroll
                for (int k2 = tt + 1; k2 < 32; ++k2) {
                    float utk = __shfl(a[k2], tt);
                    a[k2] -= lm * utk;
                }
            }
            if (lane < 32) A[(j0 + lane) * P + j0 + lane] = myinv;  // diag := 1/u_jj

            // ---- phase 2: U12 = L11^-1 * A12, column-per-lane ----
            if (bs < 3) {
                int nc = P - j0 - 32;                 // 96, 64, 32
                int c0 = j0 + 32 + lane;
                int c1 = c0 + 64;
                bool v0 = lane < nc;
                bool v1 = lane + 64 < nc;
                int c0a = v0 ? c0 : (j0 + 32);
                int c1a = v1 ? c1 : (j0 + 32);
                float ua[32], ub[32];
#pragma unroll
                for (int j = 0; j < 32; ++j) {
                    float s0 = A[(j0 + j) * P + c0a];
                    float s1 = A[(j0 + j) * P + c1a];
#pragma unroll
                    for (int t2 = 0; t2 < j; ++t2) {
                        float ljt = __shfl(a[t2], j);   // l[j][t2] from lane j
                        s0 -= ljt * ua[t2];
                        s1 -= ljt * ub[t2];
                    }
                    ua[j] = s0; ub[j] = s1;
                    if (v0) A[(j0 + j) * P + c0] = s0;
                    if (v1) A[(j0 + j) * P + c1] = s1;
                }
            }
        }
        __syncthreads();

        if (bs < 3) {
            // ---- SYRK: A22[i][k] -= sum_j U12[j][i] * invd[j] * U12[j][k] ----
            int nc = P - j0 - 32;
            int nt = nc >> 2;
            int ntiles = nt * nt;
            for (int tile = t; tile < ntiles; tile += 256) {
                int ti = tile / nt, tk = tile - ti * nt;
                int i0 = j0 + 32 + ti * 4, k0 = j0 + 32 + tk * 4;
                f32x4 acc0 = {0, 0, 0, 0}, acc1 = {0, 0, 0, 0};
                f32x4 acc2 = {0, 0, 0, 0}, acc3 = {0, 0, 0, 0};
#pragma unroll
                for (int j = 0; j < 32; ++j) {
                    const float* row = &A[(j0 + j) * P];
                    float invd = row[j0 + j];
                    f32x4 ui = *(const f32x4*)&row[i0];
                    f32x4 uk = *(const f32x4*)&row[k0];
                    uk *= invd;
                    acc0 += ui[0] * uk;
                    acc1 += ui[1] * uk;
                    acc2 += ui[2] * uk;
                    acc3 += ui[3] * uk;
                }
                f32x4* r0 = (f32x4*)&A[(i0 + 0) * P + k0];
                f32x4* r1 = (f32x4*)&A[(i0 + 1) * P + k0];
                f32x4* r2 = (f32x4*)&A[(i0 + 2) * P + k0];
                f32x4* r3 = (f32x4*)&A[(i0 + 3) * P + k0];
                *r0 -= acc0; *r1 -= acc1; *r2 -= acc2; *r3 -= acc3;
            }
            __syncthreads();
        }
    }
    if (t == 0) logd[b] = lsum;
}

// ---------------- combine ----------------
__global__ void final_kernel(const float* __restrict__ logd, const int* __restrict__ counts,
                             float* __restrict__ out, int m) {
    if (threadIdx.x == 0 && blockIdx.x == 0) {
        float empi = 0.5f * logd[0];
        float theo = 0.5f * logd[1];
        float comp = 0.f;
        for (int c = 0; c < K; ++c) {
            float cnt = (float)counts[c];
            if (cnt > 0.f) comp += logd[2 + c] * cnt / (float)m;
        }
        comp *= 0.5f;
        out[0] = GAM2 * (-empi) + comp;
        out[1] = empi;
        out[2] = theo;
        out[3] = comp;
    }
}

extern "C" void kernel_launch(void* const* d_in, const int* in_sizes, int n_in,
                              void* d_out, int out_size, void* d_ws, size_t ws_size,
                              hipStream_t stream) {
    const float* x = (const float*)d_in[0];
    const int* y = (const int*)d_in[1];
    int m = in_sizes[1];
    int nbs = (m + SORTCH - 1) / SORTCH;   // 128 sort blocks
    int nbg = (m + CH - 1) / CH + K;       // 522 gram blocks (covers worst-case padding)

    char* ws = (char*)d_ws;
    float* grams = (float*)ws;                               // K*P*P*4 = 655360
    float* logd = (float*)(ws + 655360);                     // 12 floats
    int* counts = (int*)(ws + 655424);                       // 10 ints
    int* pstart = (int*)(ws + 655488);                       // 11 ints
    int* blk_counts = (int*)(ws + 655616);                   // nbs*K
    int* blk_offsets = (int*)(ws + 655616 + (size_t)nbs * K * 4);
    int* perm = (int*)(ws + 655616 + 2 * (size_t)nbs * K * 4);   // nbg*CH ints

    hipMemsetAsync(ws, 0, 655488, stream);                       // grams + logd
    hipMemsetAsync(perm, 0xFF, (size_t)nbg * CH * 4, stream);    // perm = -1

    hist_kernel<<<nbs, NTHR, 0, stream>>>(y, blk_counts, m);
    scan_kernel<<<1, NTHR, 0, stream>>>(blk_counts, blk_offsets, counts, pstart, nbs);
    scatter_kernel<<<nbs, NTHR, 0, stream>>>(y, blk_offsets, perm, m);
    gram_kernel<<<nbg, NTHR, 0, stream>>>(x, perm, pstart, grams);
    logdet_kernel<<<K + 2, 256, 0, stream>>>(grams, counts, logd, m);
    final_kernel<<<1, 1, 0, stream>>>(logd, counts, (float*)d_out, m);
}

// Round 4
// 299.546 us; speedup vs baseline: 1.1856x; 1.1856x over previous
//
#include <hip/hip_runtime.h>

// MCR^2 loss, m x p fp32 x, labels y in [0,K). m=262144, p=128, K=10.
#define K 10
#define P 128
#define EPSV 0.01f
#define GAM1 1.0f
#define GAM2 1.0f
#define CH 512      // rows per gram block (class segments padded to multiple of CH)
#define SK 64       // staged rows (k-depth) per LDS stage
#define KS 68       // LDS k-stride in bf16 elems (64 + 4 pad, keeps b64s 2-way-free)
#define SORTCH 2048 // rows per sort block
#define NTHR 256

typedef __attribute__((ext_vector_type(8))) short bf16x8;
typedef __attribute__((ext_vector_type(4))) short s16x4;
typedef __attribute__((ext_vector_type(4))) float f32x4;

static __device__ __forceinline__ short f2bf(float f) {
    unsigned u = __float_as_uint(f);
    u = (u + 0x7FFFu + ((u >> 16) & 1u)) >> 16;   // RNE
    return (short)u;
}

// wave-uniform broadcast from a compile-time-constant lane: pure VALU->SGPR,
// ~4 cy, NO ds_bpermute round-trip (the R3 killer: serialized shfl = 117 us)
static __device__ __forceinline__ float rdlane(float v, int srclane) {
    return __int_as_float(__builtin_amdgcn_readlane(__float_as_int(v), srclane));
}

// ---------------- histogram per sort-block ----------------
__global__ void hist_kernel(const int* __restrict__ y, int* __restrict__ blk_counts, int m) {
    __shared__ int h[K];
    int t = threadIdx.x;
    if (t < K) h[t] = 0;
    __syncthreads();
    int base = blockIdx.x * SORTCH;
    int rows = min(SORTCH, m - base);
    for (int i = t; i < rows; i += NTHR) atomicAdd(&h[y[base + i]], 1);
    __syncthreads();
    if (t < K) blk_counts[blockIdx.x * K + t] = h[t];
}

// ---------------- parallel scan of block counts; padded class starts ----------
__global__ void scan_kernel(const int* __restrict__ blk_counts, int* __restrict__ blk_offsets,
                            int* __restrict__ counts, int* __restrict__ pstart, int nb) {
    __shared__ int s[K][128];
    __shared__ int sps[K + 1];
    int t = threadIdx.x;
    int own[K];
    if (t < 128) {
        for (int c = 0; c < K; ++c) {
            int v = (t < nb) ? blk_counts[t * K + c] : 0;
            own[c] = v;
            s[c][t] = v;
        }
    }
    __syncthreads();
    for (int off = 1; off < 128; off <<= 1) {
        int tmp[K];
        if (t < 128)
            for (int c = 0; c < K; ++c) tmp[c] = (t >= off) ? s[c][t - off] : 0;
        __syncthreads();
        if (t < 128)
            for (int c = 0; c < K; ++c) s[c][t] += tmp[c];
        __syncthreads();
    }
    if (t == 0) {
        int run = 0;
        for (int c = 0; c < K; ++c) {
            sps[c] = run;
            int tot = s[c][127];
            counts[c] = tot;
            pstart[c] = run;
            run += ((tot + CH - 1) / CH) * CH;   // pad each class to multiple of CH
        }
        sps[K] = run;
        pstart[K] = run;
    }
    __syncthreads();
    if (t < nb)
        for (int c = 0; c < K; ++c)
            blk_offsets[t * K + c] = sps[c] + s[c][t] - own[c];   // exclusive + padded base
}

// ---------------- scatter row indices into padded class-sorted perm -----------
__global__ void scatter_kernel(const int* __restrict__ y, const int* __restrict__ blk_offsets,
                               int* __restrict__ perm, int m) {
    __shared__ int cur[K];
    int t = threadIdx.x;
    if (t < K) cur[t] = blk_offsets[blockIdx.x * K + t];
    __syncthreads();
    int base = blockIdx.x * SORTCH;
    int rows = min(SORTCH, m - base);
    for (int i = t; i < rows; i += NTHR) {
        int row = base + i;
        int pos = atomicAdd(&cur[y[row]], 1);
        perm[pos] = row;
    }
}

// ---------------- per-class Gram via bf16 MFMA --------------------------------
__global__ __launch_bounds__(NTHR) void gram_kernel(const float* __restrict__ x,
                                                    const int* __restrict__ perm,
                                                    const int* __restrict__ pstart,
                                                    float* __restrict__ grams) {
    __shared__ int pm[CH];
    __shared__ short xsT[P * KS];   // 17408 B
    int t = threadIdx.x;
    long base = (long)blockIdx.x * CH;
    int cls = 0;
    for (int c = 1; c < K; ++c)
        if (base >= (long)pstart[c]) cls = c;
    for (int i = t; i < CH; i += NTHR) pm[i] = perm[base + i];

    const int lane = t & 63;
    const int wave = t >> 6;
    const int m16 = lane & 15;
    const int quad = lane >> 4;
    const int wr = wave >> 1;   // tile-row half (gram rows wr*64..+64)
    const int wc = wave & 1;    // tile-col half
    const int c2 = t & 63;      // staging: float2 column pair (cols 2*c2, 2*c2+1)
    const int rg = t >> 6;      // staging: row group of 16

    f32x4 acc[4][4];
#pragma unroll
    for (int a = 0; a < 4; ++a)
#pragma unroll
        for (int b = 0; b < 4; ++b) acc[a][b] = (f32x4){0.f, 0.f, 0.f, 0.f};

    __syncthreads();   // pm visible

    for (int s = 0; s < CH / SK; ++s) {
        int sb = s * SK;
        float2 v[16];
#pragma unroll
        for (int ii = 0; ii < 16; ++ii) {
            int r = pm[sb + rg * 16 + ii];
            if (r >= 0) v[ii] = ((const float2*)(x + (size_t)r * P))[c2];
            else { v[ii].x = 0.f; v[ii].y = 0.f; }
        }
        __syncthreads();   // prior stage fully consumed
        short b0[16], b1[16];
#pragma unroll
        for (int ii = 0; ii < 16; ++ii) { b0[ii] = f2bf(v[ii].x); b1[ii] = f2bf(v[ii].y); }
        int col0 = 2 * c2, col1 = 2 * c2 + 1;
#pragma unroll
        for (int q = 0; q < 4; ++q) {
            s16x4 w0 = {b0[q * 4], b0[q * 4 + 1], b0[q * 4 + 2], b0[q * 4 + 3]};
            s16x4 w1 = {b1[q * 4], b1[q * 4 + 1], b1[q * 4 + 2], b1[q * 4 + 3]};
            *(s16x4*)&xsT[col0 * KS + rg * 16 + q * 4] = w0;
            *(s16x4*)&xsT[col1 * KS + rg * 16 + q * 4] = w1;
        }
        __syncthreads();
#pragma unroll
        for (int kk = 0; kk < 2; ++kk) {
            int k0 = kk * 32 + quad * 8;
            bf16x8 af[4], bfr[4];
#pragma unroll
            for (int a = 0; a < 4; ++a) {
                int colA = wr * 64 + a * 16 + m16;
                union { bf16x8 v8; s16x4 h[2]; } u;
                u.h[0] = *(s16x4*)&xsT[colA * KS + k0];
                u.h[1] = *(s16x4*)&xsT[colA * KS + k0 + 4];
                af[a] = u.v8;
            }
#pragma unroll
            for (int b = 0; b < 4; ++b) {
                int colB = wc * 64 + b * 16 + m16;
                union { bf16x8 v8; s16x4 h[2]; } u;
                u.h[0] = *(s16x4*)&xsT[colB * KS + k0];
                u.h[1] = *(s16x4*)&xsT[colB * KS + k0 + 4];
                bfr[b] = u.v8;
            }
#pragma unroll
            for (int a = 0; a < 4; ++a)
#pragma unroll
                for (int b = 0; b < 4; ++b)
                    acc[a][b] = __builtin_amdgcn_mfma_f32_16x16x32_bf16(af[a], bfr[b], acc[a][b], 0, 0, 0);
        }
    }
    float* g = grams + (size_t)cls * P * P;
#pragma unroll
    for (int a = 0; a < 4; ++a)
#pragma unroll
        for (int b = 0; b < 4; ++b)
#pragma unroll
            for (int r = 0; r < 4; ++r) {
                int gi = wr * 64 + a * 16 + quad * 4 + r;
                int gj = wc * 64 + b * 16 + m16;
                if (gi <= gj) atomicAdd(&g[gi * P + gj], acc[a][b][r]);
            }
}

// ---------------- sum of class grams (removes 10x redundant loads in logdet) --
__global__ void sum_kernel(const float* __restrict__ grams, float* __restrict__ gsum) {
    int idx = blockIdx.x * 256 + threadIdx.x;
    float s = 0.f;
#pragma unroll
    for (int c = 0; c < K; ++c) s += grams[c * P * P + idx];
    gsum[idx] = s;
}

// ---------------- logdet(I + s*G): blocked symmetric LU, NB=32 ----------------
// phase1/phase2 run on wave 0 entirely in registers with readlane broadcasts
// (constant lane index after unroll -> pure VALU, no LDS latency).
// SYRK uses all 256 threads on row-contiguous LDS.
__global__ __launch_bounds__(256, 1) void logdet_kernel(const float* __restrict__ grams,
                                                        const float* __restrict__ gsum,
                                                        const int* __restrict__ counts,
                                                        float* __restrict__ logd, int m) {
    __shared__ float A[P * P];   // 64 KB
    int t = threadIdx.x, b = blockIdx.x;
    float scale;
    if (b == 0) scale = GAM1 * (float)P / ((float)m * EPSV);
    else if (b == 1) scale = (float)P / ((float)m * EPSV);
    else {
        float cnt = (float)counts[b - 2];
        if (cnt < 1.f) cnt = 1.f;
        scale = (float)P / (cnt * EPSV);
    }
    const float* src = (b < 2) ? gsum : (grams + (size_t)(b - 2) * P * P);
    for (int idx = t; idx < P * P; idx += 256) {
        int i = idx >> 7, c = idx & (P - 1);
        int s2 = (i <= c) ? idx : (c * P + i);   // stored upper triangle
        A[idx] = scale * src[s2] + ((i == c) ? 1.f : 0.f);
    }
    __syncthreads();

    const int lane = t & 63;
    const int wid = t >> 6;
    float lsum = 0.f;

    for (int bs = 0; bs < 4; ++bs) {
        const int j0 = bs * 32;
        if (wid == 0) {
            // ---- phase 1: in-register LU of A[j0:j0+32, j0:j0+32], row/lane --
            float a[32];
            if (lane < 32) {
#pragma unroll
                for (int cc = 0; cc < 8; ++cc)
                    *(f32x4*)&a[cc * 4] = *(f32x4*)&A[(j0 + lane) * P + j0 + cc * 4];
            } else {
#pragma unroll
                for (int cc = 0; cc < 32; ++cc) a[cc] = 0.f;
            }
            float myinv = 0.f;
#pragma unroll
            for (int tt = 0; tt < 32; ++tt) {
                float utt = rdlane(a[tt], tt);
                float inv = __builtin_amdgcn_rcpf(utt);
                lsum += __logf(utt);
                if (lane == tt) myinv = inv;
                bool act = (lane < 32) && (lane > tt);
                float lm = act ? a[tt] * inv : 0.f;
                if (act) a[tt] = lm;     // store scaled L entry (needed by phase 2)
#pragma unroll
                for (int k2 = tt + 1; k2 < 32; ++k2) {
                    float utk = rdlane(a[k2], tt);   // SGPR, ~free
                    a[k2] -= lm * utk;
                }
            }
            if (lane < 32) A[(j0 + lane) * P + j0 + lane] = myinv;  // diag := 1/u_jj

            // ---- phase 2: U12 = L11^-1 * A12, column-per-lane ----
            if (bs < 3) {
                int nc = P - j0 - 32;                 // 96, 64, 32
                int c0 = j0 + 32 + lane;
                int c1 = c0 + 64;
                bool v0 = lane < nc;
                bool v1 = lane + 64 < nc;
                int c0a = v0 ? c0 : (j0 + 32);
                int c1a = v1 ? c1 : (j0 + 32);
                float ua[32], ub[32];
                // batch all LDS reads up front (pipelined), then pure VALU
#pragma unroll
                for (int j = 0; j < 32; ++j) {
                    ua[j] = A[(j0 + j) * P + c0a];
                    ub[j] = A[(j0 + j) * P + c1a];
                }
#pragma unroll
                for (int j = 0; j < 32; ++j) {
#pragma unroll
                    for (int t2 = 0; t2 < j; ++t2) {
                        float ljt = rdlane(a[t2], j);   // l[j][t2] from lane j
                        ua[j] -= ljt * ua[t2];
                        ub[j] -= ljt * ub[t2];
                    }
                }
#pragma unroll
                for (int j = 0; j < 32; ++j) {
                    if (v0) A[(j0 + j) * P + c0] = ua[j];
                    if (v1) A[(j0 + j) * P + c1] = ub[j];
                }
            }
        }
        __syncthreads();

        if (bs < 3) {
            // ---- SYRK: A22[i][k] -= sum_j U12[j][i] * invd[j] * U12[j][k] ----
            int nc = P - j0 - 32;
            int nt = nc >> 2;
            int ntiles = nt * nt;
            for (int tile = t; tile < ntiles; tile += 256) {
                int ti = tile / nt, tk = tile - ti * nt;
                int i0 = j0 + 32 + ti * 4, k0 = j0 + 32 + tk * 4;
                f32x4 acc0 = {0, 0, 0, 0}, acc1 = {0, 0, 0, 0};
                f32x4 acc2 = {0, 0, 0, 0}, acc3 = {0, 0, 0, 0};
#pragma unroll
                for (int j = 0; j < 32; ++j) {
                    const float* row = &A[(j0 + j) * P];
                    float invd = row[j0 + j];
                    f32x4 ui = *(const f32x4*)&row[i0];
                    f32x4 uk = *(const f32x4*)&row[k0];
                    uk *= invd;
                    acc0 += ui[0] * uk;
                    acc1 += ui[1] * uk;
                    acc2 += ui[2] * uk;
                    acc3 += ui[3] * uk;
                }
                f32x4* r0 = (f32x4*)&A[(i0 + 0) * P + k0];
                f32x4* r1 = (f32x4*)&A[(i0 + 1) * P + k0];
                f32x4* r2 = (f32x4*)&A[(i0 + 2) * P + k0];
                f32x4* r3 = (f32x4*)&A[(i0 + 3) * P + k0];
                *r0 -= acc0; *r1 -= acc1; *r2 -= acc2; *r3 -= acc3;
            }
            __syncthreads();
        }
    }
    if (t == 0) logd[b] = lsum;
}

// ---------------- combine ----------------
__global__ void final_kernel(const float* __restrict__ logd, const int* __restrict__ counts,
                             float* __restrict__ out, int m) {
    if (threadIdx.x == 0 && blockIdx.x == 0) {
        float empi = 0.5f * logd[0];
        float theo = 0.5f * logd[1];
        float comp = 0.f;
        for (int c = 0; c < K; ++c) {
            float cnt = (float)counts[c];
            if (cnt > 0.f) comp += logd[2 + c] * cnt / (float)m;
        }
        comp *= 0.5f;
        out[0] = GAM2 * (-empi) + comp;
        out[1] = empi;
        out[2] = theo;
        out[3] = comp;
    }
}

extern "C" void kernel_launch(void* const* d_in, const int* in_sizes, int n_in,
                              void* d_out, int out_size, void* d_ws, size_t ws_size,
                              hipStream_t stream) {
    const float* x = (const float*)d_in[0];
    const int* y = (const int*)d_in[1];
    int m = in_sizes[1];
    int nbs = (m + SORTCH - 1) / SORTCH;   // 128 sort blocks
    int nbg = (m + CH - 1) / CH + K;       // 522 gram blocks (covers worst-case padding)

    char* ws = (char*)d_ws;
    float* grams = (float*)ws;                               // K*P*P*4 = 655360
    float* gsum = (float*)(ws + 655360);                     // P*P*4 = 65536
    float* logd = (float*)(ws + 720896);                     // 12 floats
    int* counts = (int*)(ws + 720960);                       // 10 ints
    int* pstart = (int*)(ws + 721024);                       // 11 ints
    int* blk_counts = (int*)(ws + 721152);                   // nbs*K
    int* blk_offsets = (int*)(ws + 721152 + (size_t)nbs * K * 4);
    int* perm = (int*)(ws + 721152 + 2 * (size_t)nbs * K * 4);   // nbg*CH ints

    hipMemsetAsync(ws, 0, 655360, stream);                       // grams (atomic-accumulated)
    hipMemsetAsync(perm, 0xFF, (size_t)nbg * CH * 4, stream);    // perm = -1

    hist_kernel<<<nbs, NTHR, 0, stream>>>(y, blk_counts, m);
    scan_kernel<<<1, NTHR, 0, stream>>>(blk_counts, blk_offsets, counts, pstart, nbs);
    scatter_kernel<<<nbs, NTHR, 0, stream>>>(y, blk_offsets, perm, m);
    gram_kernel<<<nbg, NTHR, 0, stream>>>(x, perm, pstart, grams);
    sum_kernel<<<P * P / 256, 256, 0, stream>>>(grams, gsum);
    logdet_kernel<<<K + 2, 256, 0, stream>>>(grams, gsum, counts, logd, m);
    final_kernel<<<1, 1, 0, stream>>>(logd, counts, (float*)d_out, m);
}